// Round 1
// baseline (1253.259 us; speedup 1.0000x reference)
//
#include <hip/hip_runtime.h>
#include <cstddef>
#include <cstdint>

#define NN 100000
#define NE 3200000
#define D  128

// ---------------- graph prep ----------------

__global__ void k_zero(int* __restrict__ p, int n) {
  int i = blockIdx.x * 256 + threadIdx.x;
  if (i < n) p[i] = 0;
}

__global__ void k_count(const int* __restrict__ dst, int* __restrict__ cnt) {
  int e = blockIdx.x * 256 + threadIdx.x;
  if (e < NE) atomicAdd(&cnt[dst[e]], 1);
}

__global__ void k_dinv(const int* __restrict__ cnt, float* __restrict__ dinv) {
  int i = blockIdx.x * 256 + threadIdx.x;
  if (i < NN) dinv[i] = rsqrtf((float)(cnt[i] + 1));  // +1 self-loop
}

__global__ void k_scan1(const int* __restrict__ cnt, int* __restrict__ tmp,
                        int* __restrict__ part) {
  __shared__ int s[256];
  int i = blockIdx.x * 256 + threadIdx.x;
  int v = (i < NN) ? cnt[i] : 0;
  s[threadIdx.x] = v;
  __syncthreads();
  for (int d = 1; d < 256; d <<= 1) {
    int t = (threadIdx.x >= d) ? s[threadIdx.x - d] : 0;
    __syncthreads();
    s[threadIdx.x] += t;
    __syncthreads();
  }
  if (i < NN) tmp[i] = s[threadIdx.x] - v;  // exclusive within block
  if (threadIdx.x == 255) part[blockIdx.x] = s[255];
}

__global__ void k_scan2(int* __restrict__ part, int nb) {
  __shared__ int s[512];
  int v = (threadIdx.x < nb) ? part[threadIdx.x] : 0;
  s[threadIdx.x] = v;
  __syncthreads();
  for (int d = 1; d < 512; d <<= 1) {
    int t = (threadIdx.x >= d) ? s[threadIdx.x - d] : 0;
    __syncthreads();
    s[threadIdx.x] += t;
    __syncthreads();
  }
  if (threadIdx.x < nb) part[threadIdx.x] = s[threadIdx.x] - v;  // exclusive
}

__global__ void k_scan3(const int* __restrict__ tmp, const int* __restrict__ part,
                        int* __restrict__ row_off, int* __restrict__ cursor) {
  int i = blockIdx.x * 256 + threadIdx.x;
  if (i < NN) {
    int r = tmp[i] + part[blockIdx.x];
    row_off[i] = r;
    cursor[i] = r;
  }
  if (blockIdx.x == 0 && threadIdx.x == 0) row_off[NN] = NE;
}

__global__ void k_fill(const int* __restrict__ src, const int* __restrict__ dst,
                       int* __restrict__ cursor, int* __restrict__ col) {
  int e = blockIdx.x * 256 + threadIdx.x;
  if (e < NE) {
    int p = atomicAdd(&cursor[dst[e]], 1);
    col[p] = src[e];
  }
}

// ---------------- dense GEMM: C[N,128] = A[N,128] @ W[128,128] ----------------
// BM=128, BN=128, Kc=32, 256 threads, 8x8 per thread.
// As stored transposed [k][row] (scalar writes, conflict-free broadcast reads).

__global__ __launch_bounds__(256) void k_gemm(const float* __restrict__ A,
                                              const float* __restrict__ W,
                                              float* __restrict__ C) {
  __shared__ float As[32][130];
  __shared__ float Bs[32][128];
  const int t  = threadIdx.x;
  const int tx = t & 15, ty = t >> 4;
  const int r0 = ty * 8, c0 = tx * 8;
  const int row0 = blockIdx.x * 128;

  float acc[8][8];
#pragma unroll
  for (int i = 0; i < 8; ++i)
#pragma unroll
    for (int j = 0; j < 8; ++j) acc[i][j] = 0.f;

  for (int kc = 0; kc < D; kc += 32) {
#pragma unroll
    for (int j = 0; j < 4; ++j) {
      int f4 = j * 256 + t;            // 0..1023
      int row = f4 >> 3, kq = f4 & 7;  // A tile: 128 rows x 8 float4
      int gr = row0 + row;
      if (gr >= NN) gr = NN - 1;       // clamp (stores are guarded)
      float4 v = *(const float4*)(A + (size_t)gr * D + kc + kq * 4);
      As[kq * 4 + 0][row] = v.x;
      As[kq * 4 + 1][row] = v.y;
      As[kq * 4 + 2][row] = v.z;
      As[kq * 4 + 3][row] = v.w;
      int kb = f4 >> 5, c4 = f4 & 31;  // B tile: 32 rows x 32 float4
      *(float4*)&Bs[kb][c4 * 4] =
          *(const float4*)(W + (size_t)(kc + kb) * D + c4 * 4);
    }
    __syncthreads();
#pragma unroll 4
    for (int k = 0; k < 32; ++k) {
      float a[8], b[8];
#pragma unroll
      for (int i = 0; i < 8; ++i) a[i] = As[k][r0 + i];
      *(float4*)(b)     = *(const float4*)&Bs[k][c0];
      *(float4*)(b + 4) = *(const float4*)&Bs[k][c0 + 4];
#pragma unroll
      for (int i = 0; i < 8; ++i)
#pragma unroll
        for (int j = 0; j < 8; ++j) acc[i][j] += a[i] * b[j];
    }
    __syncthreads();
  }
#pragma unroll
  for (int i = 0; i < 8; ++i) {
    int gr = row0 + r0 + i;
    if (gr < NN) {
      *(float4*)(C + (size_t)gr * D + c0) =
          make_float4(acc[i][0], acc[i][1], acc[i][2], acc[i][3]);
      *(float4*)(C + (size_t)gr * D + c0 + 4) =
          make_float4(acc[i][4], acc[i][5], acc[i][6], acc[i][7]);
    }
  }
}

// ---------------- aggregation: out[d] = dinv[d]*(sum_e dinv[s]*h[s] + dinv[d]*h[d]) + b ----------------
// 32 lanes per node, 4 columns per lane (float4), 8 nodes per 256-thread block.

__global__ void k_agg(const float* __restrict__ h, const int* __restrict__ row_off,
                      const int* __restrict__ col, const float* __restrict__ dinv,
                      const float* __restrict__ bias, float* __restrict__ out,
                      int relu) {
  int g = blockIdx.x * 8 + (threadIdx.x >> 5);
  if (g >= NN) return;
  int c = (threadIdx.x & 31) * 4;
  float di = dinv[g];

  float4 hs = *(const float4*)(h + (size_t)g * D + c);  // self loop
  float4 acc;
  acc.x = di * hs.x; acc.y = di * hs.y; acc.z = di * hs.z; acc.w = di * hs.w;

  int e = row_off[g], end = row_off[g + 1];
  for (; e + 2 <= end; e += 2) {
    int s0 = col[e], s1 = col[e + 1];
    float w0 = dinv[s0], w1 = dinv[s1];
    float4 v0 = *(const float4*)(h + (size_t)s0 * D + c);
    float4 v1 = *(const float4*)(h + (size_t)s1 * D + c);
    acc.x += w0 * v0.x + w1 * v1.x;
    acc.y += w0 * v0.y + w1 * v1.y;
    acc.z += w0 * v0.z + w1 * v1.z;
    acc.w += w0 * v0.w + w1 * v1.w;
  }
  for (; e < end; ++e) {
    int s0 = col[e];
    float w0 = dinv[s0];
    float4 v0 = *(const float4*)(h + (size_t)s0 * D + c);
    acc.x += w0 * v0.x; acc.y += w0 * v0.y;
    acc.z += w0 * v0.z; acc.w += w0 * v0.w;
  }
  float4 bv = *(const float4*)(bias + c);
  float4 r;
  r.x = di * acc.x + bv.x;
  r.y = di * acc.y + bv.y;
  r.z = di * acc.z + bv.z;
  r.w = di * acc.w + bv.w;
  if (relu) {
    r.x = fmaxf(r.x, 0.f); r.y = fmaxf(r.y, 0.f);
    r.z = fmaxf(r.z, 0.f); r.w = fmaxf(r.w, 0.f);
  }
  *(float4*)(out + (size_t)g * D + c) = r;
}

// ---------------- launch ----------------

extern "C" void kernel_launch(void* const* d_in, const int* in_sizes, int n_in,
                              void* d_out, int out_size, void* d_ws, size_t ws_size,
                              hipStream_t stream) {
  const float* x  = (const float*)d_in[0];
  const int*   ei = (const int*)d_in[1];
  const float* W1 = (const float*)d_in[2];
  const float* b1 = (const float*)d_in[3];
  const float* W2 = (const float*)d_in[4];
  const float* b2 = (const float*)d_in[5];
  const float* W3 = (const float*)d_in[6];
  const float* b3 = (const float*)d_in[7];
  float* out = (float*)d_out;

  char* base = (char*)d_ws;
  size_t o = 0;
  auto take = [&](size_t bytes) {
    void* p = base + o;
    o += (bytes + 255) & ~(size_t)255;
    return p;
  };
  int*   cnt     = (int*)take((size_t)NN * 4);
  int*   tmp     = (int*)take((size_t)NN * 4);
  int*   row_off = (int*)take((size_t)(NN + 1) * 4);
  int*   cursor  = (int*)take((size_t)NN * 4);
  float* dinv    = (float*)take((size_t)NN * 4);
  int*   part    = (int*)take(512 * 4);
  int*   col     = (int*)take((size_t)NE * 4);
  float* t0      = (float*)take((size_t)NN * D * 4);

  const int* src = ei;        // edge_index[0]
  const int* dst = ei + NE;   // edge_index[1]

  const int nbN = (NN + 255) / 256;  // 391
  const int nbE = (NE + 255) / 256;  // 12500

  k_zero <<<nbN, 256, 0, stream>>>(cnt, NN);
  k_count<<<nbE, 256, 0, stream>>>(dst, cnt);
  k_dinv <<<nbN, 256, 0, stream>>>(cnt, dinv);
  k_scan1<<<nbN, 256, 0, stream>>>(cnt, tmp, part);
  k_scan2<<<1, 512, 0, stream>>>(part, nbN);
  k_scan3<<<nbN, 256, 0, stream>>>(tmp, part, row_off, cursor);
  k_fill <<<nbE, 256, 0, stream>>>(src, dst, cursor, col);

  const int gB = (NN + 127) / 128;  // 782
  const int aB = (NN + 7) / 8;      // 12500

  k_gemm<<<gB, 256, 0, stream>>>(x, W1, t0);
  k_agg <<<aB, 256, 0, stream>>>(t0, row_off, col, dinv, b1, out, 1);
  k_gemm<<<gB, 256, 0, stream>>>(out, W2, t0);
  k_agg <<<aB, 256, 0, stream>>>(t0, row_off, col, dinv, b2, out, 1);
  k_gemm<<<gB, 256, 0, stream>>>(out, W3, t0);
  k_agg <<<aB, 256, 0, stream>>>(t0, row_off, col, dinv, b3, out, 0);
}

// Round 2
// 932.248 us; speedup vs baseline: 1.3443x; 1.3443x over previous
//
#include <hip/hip_runtime.h>
#include <cstddef>
#include <cstdint>

#define NN 100000
#define NE 3200000
#define D  128

// ---------------- bf16 helpers ----------------

__device__ __forceinline__ unsigned short f2bf(float f) {
  uint32_t u = __float_as_uint(f);
  uint32_t r = u + 0x7fff + ((u >> 16) & 1);   // round-to-nearest-even
  return (unsigned short)(r >> 16);
}
__device__ __forceinline__ float bf_lo(uint32_t v) {  // low bf16 of packed pair
  return __uint_as_float(v << 16);
}
__device__ __forceinline__ float bf_hi(uint32_t v) {  // high bf16 of packed pair
  return __uint_as_float(v & 0xffff0000u);
}

// ---------------- graph prep ----------------

__global__ void k_zero(int* __restrict__ p, int n) {
  int i = blockIdx.x * 256 + threadIdx.x;
  if (i < n) p[i] = 0;
}

__global__ void k_count(const int* __restrict__ dst, int* __restrict__ cnt) {
  int e = blockIdx.x * 256 + threadIdx.x;
  if (e < NE) atomicAdd(&cnt[dst[e]], 1);
}

__global__ void k_dinv(const int* __restrict__ cnt, float* __restrict__ dinv) {
  int i = blockIdx.x * 256 + threadIdx.x;
  if (i < NN) dinv[i] = rsqrtf((float)(cnt[i] + 1));  // +1 self-loop
}

__global__ void k_scan1(const int* __restrict__ cnt, int* __restrict__ tmp,
                        int* __restrict__ part) {
  __shared__ int s[256];
  int i = blockIdx.x * 256 + threadIdx.x;
  int v = (i < NN) ? cnt[i] : 0;
  s[threadIdx.x] = v;
  __syncthreads();
  for (int d = 1; d < 256; d <<= 1) {
    int t = (threadIdx.x >= d) ? s[threadIdx.x - d] : 0;
    __syncthreads();
    s[threadIdx.x] += t;
    __syncthreads();
  }
  if (i < NN) tmp[i] = s[threadIdx.x] - v;  // exclusive within block
  if (threadIdx.x == 255) part[blockIdx.x] = s[255];
}

__global__ void k_scan2(int* __restrict__ part, int nb) {
  __shared__ int s[512];
  int v = (threadIdx.x < nb) ? part[threadIdx.x] : 0;
  s[threadIdx.x] = v;
  __syncthreads();
  for (int d = 1; d < 512; d <<= 1) {
    int t = (threadIdx.x >= d) ? s[threadIdx.x - d] : 0;
    __syncthreads();
    s[threadIdx.x] += t;
    __syncthreads();
  }
  if (threadIdx.x < nb) part[threadIdx.x] = s[threadIdx.x] - v;  // exclusive
}

__global__ void k_scan3(const int* __restrict__ tmp, const int* __restrict__ part,
                        int* __restrict__ row_off, int* __restrict__ cursor) {
  int i = blockIdx.x * 256 + threadIdx.x;
  if (i < NN) {
    int r = tmp[i] + part[blockIdx.x];
    row_off[i] = r;
    cursor[i] = r;
  }
  if (blockIdx.x == 0 && threadIdx.x == 0) row_off[NN] = NE;
}

__global__ void k_fill(const int* __restrict__ src, const int* __restrict__ dst,
                       int* __restrict__ cursor, int* __restrict__ col) {
  int e = blockIdx.x * 256 + threadIdx.x;
  if (e < NE) {
    int p = atomicAdd(&cursor[dst[e]], 1);
    col[p] = src[e];
  }
}

// ---------------- dense GEMM: T[N,128](bf16) = A[N,128](f32) @ W[128,128](f32) ----------------
// BM=128, BN=128, Kc=32, 256 threads, 8x8 per thread, f32 accumulate, bf16 store.

__global__ __launch_bounds__(256) void k_gemm(const float* __restrict__ A,
                                              const float* __restrict__ W,
                                              unsigned short* __restrict__ C) {
  __shared__ float As[32][130];
  __shared__ float Bs[32][128];
  const int t  = threadIdx.x;
  const int tx = t & 15, ty = t >> 4;
  const int r0 = ty * 8, c0 = tx * 8;
  const int row0 = blockIdx.x * 128;

  float acc[8][8];
#pragma unroll
  for (int i = 0; i < 8; ++i)
#pragma unroll
    for (int j = 0; j < 8; ++j) acc[i][j] = 0.f;

  for (int kc = 0; kc < D; kc += 32) {
#pragma unroll
    for (int j = 0; j < 4; ++j) {
      int f4 = j * 256 + t;            // 0..1023
      int row = f4 >> 3, kq = f4 & 7;  // A tile: 128 rows x 8 float4
      int gr = row0 + row;
      if (gr >= NN) gr = NN - 1;       // clamp (stores are guarded)
      float4 v = *(const float4*)(A + (size_t)gr * D + kc + kq * 4);
      As[kq * 4 + 0][row] = v.x;
      As[kq * 4 + 1][row] = v.y;
      As[kq * 4 + 2][row] = v.z;
      As[kq * 4 + 3][row] = v.w;
      int kb = f4 >> 5, c4 = f4 & 31;  // B tile: 32 rows x 32 float4
      *(float4*)&Bs[kb][c4 * 4] =
          *(const float4*)(W + (size_t)(kc + kb) * D + c4 * 4);
    }
    __syncthreads();
#pragma unroll 4
    for (int k = 0; k < 32; ++k) {
      float a[8], b[8];
#pragma unroll
      for (int i = 0; i < 8; ++i) a[i] = As[k][r0 + i];
      *(float4*)(b)     = *(const float4*)&Bs[k][c0];
      *(float4*)(b + 4) = *(const float4*)&Bs[k][c0 + 4];
#pragma unroll
      for (int i = 0; i < 8; ++i)
#pragma unroll
        for (int j = 0; j < 8; ++j) acc[i][j] += a[i] * b[j];
    }
    __syncthreads();
  }
#pragma unroll
  for (int i = 0; i < 8; ++i) {
    int gr = row0 + r0 + i;
    if (gr < NN) {
      union { unsigned short us[8]; uint4 u4; } pk;
#pragma unroll
      for (int j = 0; j < 8; ++j) pk.us[j] = f2bf(acc[i][j]);
      *(uint4*)(C + (size_t)gr * D + c0) = pk.u4;  // 16B aligned: c0 % 8 == 0
    }
  }
}

// ---------------- aggregation ----------------
// out[d,:] = dinv[d]*( sum_e dinv[s]*t[s,:] + dinv[d]*t[d,:] ) + b, t in bf16.
// One 64-lane wave per node, 2 columns per lane (one packed u32), 4-edge unroll.

__global__ __launch_bounds__(256) void k_agg(
    const uint32_t* __restrict__ tu,   // bf16 rows viewed as u32 pairs [NN][64]
    const int* __restrict__ row_off, const int* __restrict__ col,
    const float* __restrict__ dinv, const float* __restrict__ bias,
    float* __restrict__ out, int relu) {
  int g = blockIdx.x * 4 + (threadIdx.x >> 6);
  if (g >= NN) return;
  int lane = threadIdx.x & 63;
  float di = dinv[g];

  uint32_t sv = tu[(size_t)g * 64 + lane];  // self row
  float a0 = di * bf_lo(sv);
  float a1 = di * bf_hi(sv);

  int e = row_off[g], end = row_off[g + 1];
  for (; e + 4 <= end; e += 4) {
    int s0 = col[e], s1 = col[e + 1], s2 = col[e + 2], s3 = col[e + 3];
    float w0 = dinv[s0], w1 = dinv[s1], w2 = dinv[s2], w3 = dinv[s3];
    uint32_t v0 = tu[(size_t)s0 * 64 + lane];
    uint32_t v1 = tu[(size_t)s1 * 64 + lane];
    uint32_t v2 = tu[(size_t)s2 * 64 + lane];
    uint32_t v3 = tu[(size_t)s3 * 64 + lane];
    a0 += w0 * bf_lo(v0); a1 += w0 * bf_hi(v0);
    a0 += w1 * bf_lo(v1); a1 += w1 * bf_hi(v1);
    a0 += w2 * bf_lo(v2); a1 += w2 * bf_hi(v2);
    a0 += w3 * bf_lo(v3); a1 += w3 * bf_hi(v3);
  }
  for (; e < end; ++e) {
    int s0 = col[e];
    float w0 = dinv[s0];
    uint32_t v0 = tu[(size_t)s0 * 64 + lane];
    a0 += w0 * bf_lo(v0); a1 += w0 * bf_hi(v0);
  }

  int c = lane * 2;
  float r0 = di * a0 + bias[c];
  float r1 = di * a1 + bias[c + 1];
  if (relu) { r0 = fmaxf(r0, 0.f); r1 = fmaxf(r1, 0.f); }
  float2 r = make_float2(r0, r1);
  *(float2*)(out + (size_t)g * D + c) = r;
}

// ---------------- launch ----------------

extern "C" void kernel_launch(void* const* d_in, const int* in_sizes, int n_in,
                              void* d_out, int out_size, void* d_ws, size_t ws_size,
                              hipStream_t stream) {
  const float* x  = (const float*)d_in[0];
  const int*   ei = (const int*)d_in[1];
  const float* W1 = (const float*)d_in[2];
  const float* b1 = (const float*)d_in[3];
  const float* W2 = (const float*)d_in[4];
  const float* b2 = (const float*)d_in[5];
  const float* W3 = (const float*)d_in[6];
  const float* b3 = (const float*)d_in[7];
  float* out = (float*)d_out;

  char* base = (char*)d_ws;
  size_t o = 0;
  auto take = [&](size_t bytes) {
    void* p = base + o;
    o += (bytes + 255) & ~(size_t)255;
    return p;
  };
  int*   cnt     = (int*)take((size_t)NN * 4);
  int*   tmp     = (int*)take((size_t)NN * 4);
  int*   row_off = (int*)take((size_t)(NN + 1) * 4);
  int*   cursor  = (int*)take((size_t)NN * 4);
  float* dinv    = (float*)take((size_t)NN * 4);
  int*   part    = (int*)take(512 * 4);
  int*   col     = (int*)take((size_t)NE * 4);
  unsigned short* t0 = (unsigned short*)take((size_t)NN * D * 2);  // bf16

  const int* src = ei;        // edge_index[0]
  const int* dst = ei + NE;   // edge_index[1]

  const int nbN = (NN + 255) / 256;  // 391
  const int nbE = (NE + 255) / 256;  // 12500

  k_zero <<<nbN, 256, 0, stream>>>(cnt, NN);
  k_count<<<nbE, 256, 0, stream>>>(dst, cnt);
  k_dinv <<<nbN, 256, 0, stream>>>(cnt, dinv);
  k_scan1<<<nbN, 256, 0, stream>>>(cnt, tmp, part);
  k_scan2<<<1, 512, 0, stream>>>(part, nbN);
  k_scan3<<<nbN, 256, 0, stream>>>(tmp, part, row_off, cursor);
  k_fill <<<nbE, 256, 0, stream>>>(src, dst, cursor, col);

  const int gB = (NN + 127) / 128;  // 782
  const int aB = (NN + 3) / 4;      // 25000

  k_gemm<<<gB, 256, 0, stream>>>(x, W1, t0);
  k_agg <<<aB, 256, 0, stream>>>((const uint32_t*)t0, row_off, col, dinv, b1, out, 1);
  k_gemm<<<gB, 256, 0, stream>>>(out, W2, t0);
  k_agg <<<aB, 256, 0, stream>>>((const uint32_t*)t0, row_off, col, dinv, b2, out, 1);
  k_gemm<<<gB, 256, 0, stream>>>(out, W3, t0);
  k_agg <<<aB, 256, 0, stream>>>((const uint32_t*)t0, row_off, col, dinv, b3, out, 0);
}

// Round 3
// 627.604 us; speedup vs baseline: 1.9969x; 1.4854x over previous
//
#include <hip/hip_runtime.h>
#include <cstddef>
#include <cstdint>

#define NN 100000
#define NE 3200000
#define D  128
#define NB 782          // ceil(NN / 128) dst-buckets of 128 nodes
#define BSH 7
#define NPB 512         // partition blocks
#define CHUNK 6250      // ceil(NE / NPB)

// ---------------- bf16 helpers ----------------

__device__ __forceinline__ unsigned short f2bf(float f) {
  uint32_t u = __float_as_uint(f);
  uint32_t r = u + 0x7fff + ((u >> 16) & 1);   // round-to-nearest-even
  return (unsigned short)(r >> 16);
}
__device__ __forceinline__ float bf_lo(uint32_t v) {
  return __uint_as_float(v << 16);
}
__device__ __forceinline__ float bf_hi(uint32_t v) {
  return __uint_as_float(v & 0xffff0000u);
}

// ---------------- graph prep: bucketed binning ----------------

__global__ void kb_zero(int* __restrict__ gb) {
  int i = blockIdx.x * 256 + threadIdx.x;
  if (i < NB) gb[i] = 0;
}

__global__ __launch_bounds__(256) void kb_count(const int* __restrict__ dst,
                                                int* __restrict__ gb) {
  __shared__ int h[NB];
  for (int i = threadIdx.x; i < NB; i += 256) h[i] = 0;
  __syncthreads();
  int lo = blockIdx.x * CHUNK, hi = lo + CHUNK;
  if (hi > NE) hi = NE;
  for (int e = lo + threadIdx.x; e < hi; e += 256)
    atomicAdd(&h[dst[e] >> BSH], 1);
  __syncthreads();
  for (int i = threadIdx.x; i < NB; i += 256)
    if (h[i]) atomicAdd(&gb[i], h[i]);
}

__global__ __launch_bounds__(1024) void kb_scan(const int* __restrict__ gb,
                                                int* __restrict__ boff,
                                                int* __restrict__ gcur) {
  __shared__ int s[1024];
  int t = threadIdx.x;
  int v = (t < NB) ? gb[t] : 0;
  s[t] = v;
  __syncthreads();
  for (int d = 1; d < 1024; d <<= 1) {
    int u = (t >= d) ? s[t - d] : 0;
    __syncthreads();
    s[t] += u;
    __syncthreads();
  }
  if (t < NB) {
    int x = s[t] - v;   // exclusive
    boff[t] = x;
    gcur[t] = x;
  }
  if (t == 0) boff[NB] = NE;
}

__global__ __launch_bounds__(256) void kb_part(const int* __restrict__ src,
                                               const int* __restrict__ dst,
                                               int* __restrict__ gcur,
                                               uint2* __restrict__ ebuf) {
  __shared__ int h[NB];
  __shared__ int cur[NB];
  for (int i = threadIdx.x; i < NB; i += 256) h[i] = 0;
  __syncthreads();
  int lo = blockIdx.x * CHUNK, hi = lo + CHUNK;
  if (hi > NE) hi = NE;
  for (int e = lo + threadIdx.x; e < hi; e += 256)
    atomicAdd(&h[dst[e] >> BSH], 1);
  __syncthreads();
  for (int i = threadIdx.x; i < NB; i += 256)
    cur[i] = h[i] ? atomicAdd(&gcur[i], h[i]) : 0;
  __syncthreads();
  for (int e = lo + threadIdx.x; e < hi; e += 256) {
    int s = src[e], d = dst[e];
    int p = atomicAdd(&cur[d >> BSH], 1);
    ebuf[p] = make_uint2((unsigned)s, (unsigned)d);
  }
}

__global__ __launch_bounds__(256) void kb_nodecnt(const uint2* __restrict__ ebuf,
                                                  const int* __restrict__ boff,
                                                  int* __restrict__ cnt) {
  int b = blockIdx.x;
  __shared__ int h[128];
  if (threadIdx.x < 128) h[threadIdx.x] = 0;
  __syncthreads();
  int lo = boff[b], hi = boff[b + 1];
  for (int e = lo + threadIdx.x; e < hi; e += 256)
    atomicAdd(&h[ebuf[e].y & 127], 1);
  __syncthreads();
  int node = b * 128 + threadIdx.x;
  if (threadIdx.x < 128 && node < NN) cnt[node] = h[threadIdx.x];
}

__global__ void k_dinv(const int* __restrict__ cnt, float* __restrict__ dinv) {
  int i = blockIdx.x * 256 + threadIdx.x;
  if (i < NN) dinv[i] = rsqrtf((float)(cnt[i] + 1));  // +1 self-loop
}

__global__ void k_scan1(const int* __restrict__ cnt, int* __restrict__ tmp,
                        int* __restrict__ part) {
  __shared__ int s[256];
  int i = blockIdx.x * 256 + threadIdx.x;
  int v = (i < NN) ? cnt[i] : 0;
  s[threadIdx.x] = v;
  __syncthreads();
  for (int d = 1; d < 256; d <<= 1) {
    int t = (threadIdx.x >= d) ? s[threadIdx.x - d] : 0;
    __syncthreads();
    s[threadIdx.x] += t;
    __syncthreads();
  }
  if (i < NN) tmp[i] = s[threadIdx.x] - v;
  if (threadIdx.x == 255) part[blockIdx.x] = s[255];
}

__global__ void k_scan2(int* __restrict__ part, int nb) {
  __shared__ int s[512];
  int v = (threadIdx.x < nb) ? part[threadIdx.x] : 0;
  s[threadIdx.x] = v;
  __syncthreads();
  for (int d = 1; d < 512; d <<= 1) {
    int t = (threadIdx.x >= d) ? s[threadIdx.x - d] : 0;
    __syncthreads();
    s[threadIdx.x] += t;
    __syncthreads();
  }
  if (threadIdx.x < nb) part[threadIdx.x] = s[threadIdx.x] - v;
}

__global__ void k_scan3(const int* __restrict__ tmp, const int* __restrict__ part,
                        int* __restrict__ row_off) {
  int i = blockIdx.x * 256 + threadIdx.x;
  if (i < NN) row_off[i] = tmp[i] + part[blockIdx.x];
  if (blockIdx.x == 0 && threadIdx.x == 0) row_off[NN] = NE;
}

__global__ __launch_bounds__(256) void kb_fill(const uint2* __restrict__ ebuf,
                                               const int* __restrict__ boff,
                                               const int* __restrict__ row_off,
                                               int* __restrict__ col) {
  int b = blockIdx.x;
  __shared__ int cur[128];
  int node = b * 128 + threadIdx.x;
  if (threadIdx.x < 128) cur[threadIdx.x] = (node < NN) ? row_off[node] : 0;
  __syncthreads();
  int lo = boff[b], hi = boff[b + 1];
  for (int e = lo + threadIdx.x; e < hi; e += 256) {
    uint2 p = ebuf[e];
    int pos = atomicAdd(&cur[p.y & 127], 1);
    col[pos] = (int)p.x;
  }
}

// ---------------- dense GEMM: T[N,128](bf16) = dinv[row] * (A[N,128] @ W[128,128]) ----------------

__global__ __launch_bounds__(256) void k_gemm(const float* __restrict__ A,
                                              const float* __restrict__ W,
                                              const float* __restrict__ dinv,
                                              unsigned short* __restrict__ C) {
  __shared__ float As[32][130];
  __shared__ float Bs[32][128];
  const int t  = threadIdx.x;
  const int tx = t & 15, ty = t >> 4;
  const int r0 = ty * 8, c0 = tx * 8;
  const int row0 = blockIdx.x * 128;

  float acc[8][8];
#pragma unroll
  for (int i = 0; i < 8; ++i)
#pragma unroll
    for (int j = 0; j < 8; ++j) acc[i][j] = 0.f;

  for (int kc = 0; kc < D; kc += 32) {
#pragma unroll
    for (int j = 0; j < 4; ++j) {
      int f4 = j * 256 + t;
      int row = f4 >> 3, kq = f4 & 7;
      int gr = row0 + row;
      if (gr >= NN) gr = NN - 1;
      float4 v = *(const float4*)(A + (size_t)gr * D + kc + kq * 4);
      As[kq * 4 + 0][row] = v.x;
      As[kq * 4 + 1][row] = v.y;
      As[kq * 4 + 2][row] = v.z;
      As[kq * 4 + 3][row] = v.w;
      int kb = f4 >> 5, c4 = f4 & 31;
      *(float4*)&Bs[kb][c4 * 4] =
          *(const float4*)(W + (size_t)(kc + kb) * D + c4 * 4);
    }
    __syncthreads();
#pragma unroll 4
    for (int k = 0; k < 32; ++k) {
      float a[8], b[8];
#pragma unroll
      for (int i = 0; i < 8; ++i) a[i] = As[k][r0 + i];
      *(float4*)(b)     = *(const float4*)&Bs[k][c0];
      *(float4*)(b + 4) = *(const float4*)&Bs[k][c0 + 4];
#pragma unroll
      for (int i = 0; i < 8; ++i)
#pragma unroll
        for (int j = 0; j < 8; ++j) acc[i][j] += a[i] * b[j];
    }
    __syncthreads();
  }
#pragma unroll
  for (int i = 0; i < 8; ++i) {
    int gr = row0 + r0 + i;
    if (gr < NN) {
      float di = dinv[gr];
      union { unsigned short us[8]; uint4 u4; } pk;
#pragma unroll
      for (int j = 0; j < 8; ++j) pk.us[j] = f2bf(di * acc[i][j]);
      *(uint4*)(C + (size_t)gr * D + c0) = pk.u4;
    }
  }
}

// ---------------- aggregation ----------------
// t[s] = dinv[s]*(hW)[s] (bf16). out[d,:] = dinv[d]*(sum_{s in N(d)} t[s] + t[d]) + b.

__global__ __launch_bounds__(256) void k_agg(
    const uint32_t* __restrict__ tu,
    const int* __restrict__ row_off, const int* __restrict__ col,
    const float* __restrict__ dinv, const float* __restrict__ bias,
    float* __restrict__ out, int relu) {
  int g = blockIdx.x * 4 + (threadIdx.x >> 6);
  if (g >= NN) return;
  int lane = threadIdx.x & 63;
  float di = dinv[g];

  uint32_t sv = tu[(size_t)g * 64 + lane];  // self (already dinv-scaled)
  float a0 = bf_lo(sv);
  float a1 = bf_hi(sv);

  int e = row_off[g], end = row_off[g + 1];
  for (; e + 4 <= end; e += 4) {
    int s0 = col[e], s1 = col[e + 1], s2 = col[e + 2], s3 = col[e + 3];
    uint32_t v0 = tu[(size_t)s0 * 64 + lane];
    uint32_t v1 = tu[(size_t)s1 * 64 + lane];
    uint32_t v2 = tu[(size_t)s2 * 64 + lane];
    uint32_t v3 = tu[(size_t)s3 * 64 + lane];
    a0 += bf_lo(v0); a1 += bf_hi(v0);
    a0 += bf_lo(v1); a1 += bf_hi(v1);
    a0 += bf_lo(v2); a1 += bf_hi(v2);
    a0 += bf_lo(v3); a1 += bf_hi(v3);
  }
  for (; e < end; ++e) {
    uint32_t v0 = tu[(size_t)col[e] * 64 + lane];
    a0 += bf_lo(v0); a1 += bf_hi(v0);
  }

  int c = lane * 2;
  float r0 = di * a0 + bias[c];
  float r1 = di * a1 + bias[c + 1];
  if (relu) { r0 = fmaxf(r0, 0.f); r1 = fmaxf(r1, 0.f); }
  *(float2*)(out + (size_t)g * D + c) = make_float2(r0, r1);
}

// ---------------- launch ----------------

extern "C" void kernel_launch(void* const* d_in, const int* in_sizes, int n_in,
                              void* d_out, int out_size, void* d_ws, size_t ws_size,
                              hipStream_t stream) {
  const float* x  = (const float*)d_in[0];
  const int*   ei = (const int*)d_in[1];
  const float* W1 = (const float*)d_in[2];
  const float* b1 = (const float*)d_in[3];
  const float* W2 = (const float*)d_in[4];
  const float* b2 = (const float*)d_in[5];
  const float* W3 = (const float*)d_in[6];
  const float* b3 = (const float*)d_in[7];
  float* out = (float*)d_out;

  char* base = (char*)d_ws;
  size_t o = 0;
  auto take = [&](size_t bytes) {
    void* p = base + o;
    o += (bytes + 255) & ~(size_t)255;
    return p;
  };
  int*   cnt     = (int*)take((size_t)NN * 4);
  int*   tmp     = (int*)take((size_t)NN * 4);
  int*   row_off = (int*)take((size_t)(NN + 1) * 4);
  float* dinv    = (float*)take((size_t)NN * 4);
  int*   part    = (int*)take(512 * 4);
  int*   gb      = (int*)take((size_t)NB * 4);
  int*   boff    = (int*)take((size_t)(NB + 1) * 4);
  int*   gcur    = (int*)take((size_t)NB * 4);
  uint2* ebuf    = (uint2*)take((size_t)NE * 8);
  int*   col     = (int*)take((size_t)NE * 4);
  unsigned short* t0 = (unsigned short*)take((size_t)NN * D * 2);

  const int* src = ei;        // edge_index[0]
  const int* dst = ei + NE;   // edge_index[1]

  const int nbN = (NN + 255) / 256;  // 391

  kb_zero   <<<(NB + 255) / 256, 256, 0, stream>>>(gb);
  kb_count  <<<NPB, 256, 0, stream>>>(dst, gb);
  kb_scan   <<<1, 1024, 0, stream>>>(gb, boff, gcur);
  kb_part   <<<NPB, 256, 0, stream>>>(src, dst, gcur, ebuf);
  kb_nodecnt<<<NB, 256, 0, stream>>>(ebuf, boff, cnt);
  k_dinv    <<<nbN, 256, 0, stream>>>(cnt, dinv);
  k_scan1   <<<nbN, 256, 0, stream>>>(cnt, tmp, part);
  k_scan2   <<<1, 512, 0, stream>>>(part, nbN);
  k_scan3   <<<nbN, 256, 0, stream>>>(tmp, part, row_off);
  kb_fill   <<<NB, 256, 0, stream>>>(ebuf, boff, row_off, col);

  const int gB = (NN + 127) / 128;  // 782
  const int aB = (NN + 3) / 4;      // 25000

  k_gemm<<<gB, 256, 0, stream>>>(x, W1, dinv, t0);
  k_agg <<<aB, 256, 0, stream>>>((const uint32_t*)t0, row_off, col, dinv, b1, out, 1);
  k_gemm<<<gB, 256, 0, stream>>>(out, W2, dinv, t0);
  k_agg <<<aB, 256, 0, stream>>>((const uint32_t*)t0, row_off, col, dinv, b2, out, 1);
  k_gemm<<<gB, 256, 0, stream>>>(out, W3, dinv, t0);
  k_agg <<<aB, 256, 0, stream>>>((const uint32_t*)t0, row_off, col, dinv, b3, out, 0);
}